// Round 7
// baseline (438.748 us; speedup 1.0000x reference)
//
#include <hip/hip_runtime.h>

#define DEV static __device__ __forceinline__

struct Cx { float r, i; };
DEV Cx cmul(Cx a, Cx b){ Cx o; o.r = a.r*b.r - a.i*b.i; o.i = a.r*b.i + a.i*b.r; return o; }

// ---- DPP helpers (row = 16 lanes). Only modes proven passing (R1/R4/R6). ----
template<int CTRL>
DEV float dppf(float x){
  int v = __builtin_amdgcn_update_dpp(0, __builtin_bit_cast(int, x), CTRL, 0xF, 0xF, true);
  return __builtin_bit_cast(float, v);
}
// sum over each 16-lane row; every lane of the row gets the full row sum
DEV float rowsum16(float v){
  v += dppf<0xB1>(v);    // quad_perm(1,0,3,2): xor 1
  v += dppf<0x4E>(v);    // quad_perm(2,3,0,1): xor 2
  v += dppf<0x124>(v);   // row_ror:4
  v += dppf<0x128>(v);   // row_ror:8
  return v;
}
// sum over the 4 stride-4 groups within a 16-lane row (keeps lane&3 fixed)
DEV float chunksum4(float v){
  v += dppf<0x124>(v);   // row_ror:4
  v += dppf<0x128>(v);   // row_ror:8
  return v;
}
// cross-row exchange via ds_bpermute (__shfl_xor proven in R1); NO v_readlane in loop.
DEV float sx16(float v){ return __shfl_xor(v, 16); }
DEV float sx32(float v){ return __shfl_xor(v, 32); }
// full 64-lane sum, broadcast to all lanes
DEV float full64(float v){
  float r = rowsum16(v);
  r += sx16(r);
  r += sx32(r);
  return r;
}

DEV float fexp(float x){ return __builtin_amdgcn_exp2f(x * 1.44269504088896341f); }
DEV float frcp(float x){ return __builtin_amdgcn_rcpf(x); }
DEV float frsq(float x){ return __builtin_amdgcn_rsqf(x); }
DEV float fsqrt_(float x){ return __builtin_amdgcn_sqrtf(x); }
DEV float sigmoidf_(float x){ return frcp(1.f + fexp(-x)); }
DEV float tanhfast(float x){ return 1.f - 2.f*frcp(1.f + fexp(2.f*x)); }

// qubit i <-> bit (3-i) of the 16-amplitude index.
__global__ void __launch_bounds__(64) qssm(
  const float* __restrict__ x,  const float* __restrict__ fw,
  const float* __restrict__ ew, const float* __restrict__ eb,
  const float* __restrict__ exw,const float* __restrict__ exb,
  const float* __restrict__ vw, const float* __restrict__ nrw,
  const float* __restrict__ nrb,float* __restrict__ out,
  int T, long long hToff)
{
  const int lane = threadIdx.x;      // 0..63
  const int blk  = blockIdx.x;       // batch element
  const int r    = lane >> 4;        // row
  const int k    = 4*r + (lane & 3); // amplitude this lane owns (F-matvec)
  const int c    = (lane >> 2) & 3;  // j-chunk this lane sums

  // ---------- build fixed circuit matrix M (16x16 complex) once ----------
  __shared__ float MrS[16][16];
  __shared__ float MiS[16][16];
  if (lane < 16){
    const int j = lane;              // simulate column j
    float w2[2][3][4];
    #pragma unroll
    for (int l=0;l<2;l++)
      #pragma unroll
      for (int g=0;g<3;g++)
        #pragma unroll
        for (int i=0;i<4;i++) w2[l][g][i] = 0.5f * vw[(l*3+g)*4+i];
    float sr[16], si[16];
    #pragma unroll
    for (int n=0;n<16;n++){ sr[n] = (n==j)?1.f:0.f; si[n]=0.f; }
    #pragma unroll
    for (int l=0;l<2;l++){
      #pragma unroll
      for (int cq=0;cq<4;cq++){
        const int tq=(cq+1)&3, mc=1<<(3-cq), mt=1<<(3-tq);
        #pragma unroll
        for (int n=0;n<16;n++){
          if ((n&mc) && !(n&mt)){
            const int n1 = n|mt;
            float tr=sr[n], ti=si[n];
            sr[n]=sr[n1]; si[n]=si[n1];
            sr[n1]=tr;    si[n1]=ti;
          }
        }
      }
      #pragma unroll
      for (int i=0;i<4;i++){
        const int m=1<<(3-i);
        const float cx=cosf(w2[l][0][i]), sx=sinf(w2[l][0][i]);
        const float cy=cosf(w2[l][1][i]), sy=sinf(w2[l][1][i]);
        const float cz=cosf(w2[l][2][i]), sz=sinf(w2[l][2][i]);
        #pragma unroll
        for (int n=0;n<16;n++){
          if (!(n&m)){
            const int n1=n|m;
            float a0r=sr[n], a0i=si[n], a1r=sr[n1], a1i=si[n1];
            float b0r = cx*a0r + sx*a1i, b0i = cx*a0i - sx*a1r;
            float b1r = sx*a0i + cx*a1r, b1i = -sx*a0r + cx*a1i;
            float c0r = cy*b0r - sy*b1r, c0i = cy*b0i - sy*b1i;
            float c1r = sy*b0r + cy*b1r, c1i = sy*b0i + cy*b1i;
            sr[n]  = cz*c0r + sz*c0i;  si[n]  = cz*c0i - sz*c0r;
            sr[n1] = cz*c1r - sz*c1i;  si[n1] = cz*c1i + sz*c1r;
          }
        }
      }
    }
    #pragma unroll
    for (int n=0;n<16;n++){ MrS[n][j]=sr[n]; MiS[n][j]=si[n]; }
  }
  __syncthreads();

  // M fragment: row k, columns 4c..4c+3
  float Mr[4], Mi[4];
  #pragma unroll
  for (int m=0;m<4;m++){ Mr[m]=MrS[k][4*c+m]; Mi[m]=MiS[k][4*c+m]; }

  // ---------- per-lane weight registers ----------
  // x-dot: lane covers x-cols {2*lane, 2*lane+1} for ALL 4 qubits (exact 1x read)
  float Wx4[4][2];
  #pragma unroll
  for (int q=0;q<4;q++)
    #pragma unroll
    for (int m=0;m<2;m++){
      const int col = 2*lane + m;
      Wx4[q][m] = ew[q*192 + col] * fexp(fw[col]);
    }
  const float e0b = eb[0], e1b = eb[1], e2b = eb[2], e3b = eb[3];

  // entry h-columns folded through LayerNorm:
  // hdot_q = rstd*(S_q - mu*C1_q) + C2_q,  S_q = sum(Wh_q*lw*pre)
  const float lw = nrw[lane], lb = nrb[lane];
  float WL[4], C1[4], C2[4];
  #pragma unroll
  for (int q=0;q<4;q++){
    const float whq = ew[q*192 + 128 + lane];
    WL[q] = whq * lw;
    C1[q] = full64(WL[q]);
    C2[q] = full64(whq * lb);
  }

  // exit rows: lane -> g_lane, i_lane, d_lane
  float Wo0[4], Wo1[4], Wo2[4];
  #pragma unroll
  for (int m=0;m<4;m++){
    Wo0[m] = exw[(lane      )*4+m];
    Wo1[m] = exw[(64  + lane)*4+m];
    Wo2[m] = exw[(128 + lane)*4+m];
  }
  const float bo0 = exb[lane], bo1 = exb[64+lane], bo2 = exb[128+lane];

  // pre-scaled Z-expectation signs (0.25: each p_k appears 4x in its row)
  const float sg0 = (lane & 32) ? -0.25f : 0.25f;   // k bit3 (row-pair sign)
  const float sg1 = (lane & 16) ? -0.25f : 0.25f;   // k bit2 (row parity sign)
  const float sg2 = (lane &  2) ? -0.25f : 0.25f;   // k bit1 (in-row)
  const float sg3 = (lane &  1) ? -0.25f : 0.25f;   // k bit0 (in-row)

  const float* xq = x + (size_t)blk * T * 128 + 2*lane;  // lane's 2-col base
  float* op = out + (size_t)blk * T * 64 + lane;

  // recurrent state
  float S0=0.f, S1=0.f, S2=0.f, S3=0.f;   // sum WL_q * pre
  float mu=0.f, rstd=0.f, w0=0.f;         // LN scalars (w0 gates C2 on step 0)
  float cst=0.f, h=0.f;
  float Yx0, Yx1, Yx2, Yx3;

  // ---- preamble: Yx(0) from x(0); prime xrA = x(1) ----
  float xrA[2], xrB[2];
  {
    const float x0 = xq[0], x1 = xq[1];
    const float a0 = fmaf(Wx4[0][1],x1, Wx4[0][0]*x0);
    const float a1 = fmaf(Wx4[1][1],x1, Wx4[1][0]*x0);
    const float a2 = fmaf(Wx4[2][1],x1, Wx4[2][0]*x0);
    const float a3 = fmaf(Wx4[3][1],x1, Wx4[3][0]*x0);
    Yx0 = full64(a0) + e0b; Yx1 = full64(a1) + e1b;
    Yx2 = full64(a2) + e2b; Yx3 = full64(a3) + e3b;
  }
  xrA[0] = xq[128]; xrA[1] = xq[129];   // x(1)

  // STEP(TCUR, XU, XL): top issues loads x(TCUR+2)->XL; bottom consumes XU(=x(TCUR+1)).
#define STEP(TCUR, XU, XL)                                                         \
  {                                                                                \
    const int t_ = (TCUR);                                                         \
    /* y_q = Yx_q + hdot_q (LN-folded) */                                          \
    const float y0 = Yx0 + fmaf(w0, C2[0], rstd*fmaf(-mu, C1[0], S0));             \
    const float y1 = Yx1 + fmaf(w0, C2[1], rstd*fmaf(-mu, C1[1], S1));             \
    const float y2 = Yx2 + fmaf(w0, C2[2], rstd*fmaf(-mu, C1[2], S2));             \
    const float y3 = Yx3 + fmaf(w0, C2[3], rstd*fmaf(-mu, C1[3], S3));             \
    /* issue prefetch loads for t_+2 (consumed 2 steps from now) */                \
    {                                                                              \
      const int tn = (t_+2 < T) ? (t_+2) : (T-1);                                  \
      const float* xsrc = xq + (size_t)tn*128;                                     \
      XL[0] = xsrc[0]; XL[1] = xsrc[1];                                            \
    }                                                                              \
    /* exit y-part (runs parallel with VQC chain) */                               \
    const float oy0 = fmaf(Wo0[3],y3, fmaf(Wo0[2],y2, fmaf(Wo0[1],y1, fmaf(Wo0[0],y0, bo0)))); \
    const float oy1 = fmaf(Wo1[3],y3, fmaf(Wo1[2],y2, fmaf(Wo1[1],y1, fmaf(Wo1[0],y0, bo1)))); \
    const float oy2 = fmaf(Wo2[3],y3, fmaf(Wo2[2],y2, fmaf(Wo2[1],y1, fmaf(Wo2[0],y0, bo2)))); \
    /* encoded qubit vectors, phase-rotated so the |0> comp is real */             \
    float a0_,a1_,a2_,a3_;  Cx b0_,b1_,b2_,b3_;                                    \
    {                                                                              \
      auto mkv = [&](float u, float& a, Cx& b){                                    \
        const float r2 = u*u;                                                      \
        const float c1 = frsq(fmaf(u,u,1.f));                                      \
        const float tt = (0.5f*u)*c1;                                              \
        a = fsqrt_(fmaxf(0.5f - tt, 0.f));                                         \
        const float bb = fsqrt_(0.5f + tt);                                        \
        const float cp = frsq(fmaf(r2,r2,1.f));                                    \
        const float sp = r2*cp;                                                    \
        b.r = bb*cp; b.i = bb*sp;                                                  \
      };                                                                           \
      mkv(y0,a0_,b0_); mkv(y1,a1_,b1_); mkv(y2,a2_,b2_); mkv(y3,a3_,b3_);          \
    }                                                                              \
    /* psi0[j], j = 4c + m */                                                      \
    Cx sel0, sel1;                                                                 \
    sel0.r = (lane & 8) ? b0_.r : a0_;  sel0.i = (lane & 8) ? b0_.i : 0.f;         \
    sel1.r = (lane & 4) ? b1_.r : a1_;  sel1.i = (lane & 4) ? b1_.i : 0.f;         \
    const Cx A = cmul(sel0, sel1);                                                 \
    Cx B0, B1, B2, B3;                                                             \
    B0.r = a2_*a3_;            B0.i = 0.f;                                         \
    B1.r = a2_*b3_.r;          B1.i = a2_*b3_.i;                                   \
    B2.r = b2_.r*a3_;          B2.i = b2_.i*a3_;                                   \
    B3 = cmul(b2_, b3_);                                                           \
    const Cx p0 = cmul(A,B0), p1 = cmul(A,B1), p2 = cmul(A,B2), p3 = cmul(A,B3);   \
    /* F_k partial over j=4c..4c+3, then in-row chunk reduction (DPP only) */      \
    float t0r = fmaf(-p0.i, Mi[0], p0.r*Mr[0]);                                    \
    float t1r = fmaf(-p1.i, Mi[1], p1.r*Mr[1]);                                    \
    float t2r = fmaf(-p2.i, Mi[2], p2.r*Mr[2]);                                    \
    float t3r = fmaf(-p3.i, Mi[3], p3.r*Mr[3]);                                    \
    float t0i = fmaf( p0.i, Mr[0], p0.r*Mi[0]);                                    \
    float t1i = fmaf( p1.i, Mr[1], p1.r*Mi[1]);                                    \
    float t2i = fmaf( p2.i, Mr[2], p2.r*Mi[2]);                                    \
    float t3i = fmaf( p3.i, Mr[3], p3.r*Mi[3]);                                    \
    const float Fr = chunksum4((t0r+t1r)+(t2r+t3r));                               \
    const float Fi = chunksum4((t0i+t1i)+(t2i+t3i));                               \
    const float p = fmaf(Fr,Fr, Fi*Fi);                                            \
    /* Z expectations: q0/q1 from shared rowsum16(p); q2/q3 pre-signed; no rdl */  \
    const float rsp = rowsum16(p);           /* = 4*P_row at every lane */         \
    const float rs2 = rowsum16(sg2*p);                                             \
    const float rs3 = rowsum16(sg3*p);                                             \
    const float Apair = rsp + sx16(rsp);     /* 4(P0+P1) | 4(P2+P3) */             \
    const float Dpair = sg1*(rsp - sx16(rsp)); /* (P0-P1) | (P2-P3), 0.25-scaled */ \
    const float u2 = rs2 + sx16(rs2);                                              \
    const float u3 = rs3 + sx16(rs3);                                              \
    const float q0 = sg0*(Apair - sx32(Apair));                                    \
    const float q1 = Dpair + sx32(Dpair);                                          \
    const float q2 = u2 + sx32(u2);                                                \
    const float q3 = u3 + sx32(u3);                                                \
    /* exit q-part + gates */                                                      \
    const float og = fmaf(Wo0[3],q3, fmaf(Wo0[2],q2, fmaf(Wo0[1],q1, fmaf(Wo0[0],q0, oy0)))); \
    const float oi = fmaf(Wo1[3],q3, fmaf(Wo1[2],q2, fmaf(Wo1[1],q1, fmaf(Wo1[0],q0, oy1)))); \
    const float od = fmaf(Wo2[3],q3, fmaf(Wo2[2],q2, fmaf(Wo2[1],q1, fmaf(Wo2[0],q0, oy2)))); \
    float g = sigmoidf_(og);                                                       \
    g = fminf(fmaxf(g, 0.05f), 0.95f);                                             \
    const float ig = sigmoidf_(oi);                                                \
    const float dt = tanhfast(od);                                                 \
    cst = fmaf(fmaf(-0.9f, g, 0.9f), cst, ig*dt);                                  \
    const float pre = g * tanhfast(cst);                                           \
    /* fused LN + next-entry reductions (6 independent, shfl-pipelined) */         \
    float s1 = rowsum16(pre);                                                      \
    float s2 = rowsum16(pre*pre);                                                  \
    float T0 = rowsum16(WL[0]*pre);                                                \
    float T1 = rowsum16(WL[1]*pre);                                                \
    float T2 = rowsum16(WL[2]*pre);                                                \
    float T3 = rowsum16(WL[3]*pre);                                                \
    s1 += sx16(s1); s2 += sx16(s2);                                                \
    T0 += sx16(T0); T1 += sx16(T1); T2 += sx16(T2); T3 += sx16(T3);                \
    s1 += sx32(s1); s2 += sx32(s2);                                                \
    T0 += sx32(T0); T1 += sx32(T1); T2 += sx32(T2); T3 += sx32(T3);                \
    S0=T0; S1=T1; S2=T2; S3=T3;                                                    \
    mu = s1 * (1.f/64.f);                                                          \
    const float var = fmaf(s2, 1.f/64.f, -mu*mu);                                  \
    rstd = frsq(var + 1e-5f);                                                      \
    h = fmaf((pre - mu)*rstd, lw, lb);                                             \
    op[(size_t)t_*64] = h;                                                         \
    w0 = 1.f;                                                                      \
    /* bottom: next Yx from XU (=x(t_+1)); full64 reduce, no readlane */           \
    {                                                                              \
      float a0 = fmaf(Wx4[0][1],XU[1], Wx4[0][0]*XU[0]);                           \
      float a1 = fmaf(Wx4[1][1],XU[1], Wx4[1][0]*XU[0]);                           \
      float a2 = fmaf(Wx4[2][1],XU[1], Wx4[2][0]*XU[0]);                           \
      float a3 = fmaf(Wx4[3][1],XU[1], Wx4[3][0]*XU[0]);                           \
      a0 = rowsum16(a0); a1 = rowsum16(a1); a2 = rowsum16(a2); a3 = rowsum16(a3);  \
      a0 += sx16(a0); a1 += sx16(a1); a2 += sx16(a2); a3 += sx16(a3);              \
      a0 += sx32(a0); a1 += sx32(a1); a2 += sx32(a2); a3 += sx32(a3);              \
      Yx0 = a0 + e0b; Yx1 = a1 + e1b; Yx2 = a2 + e2b; Yx3 = a3 + e3b;              \
    }                                                                              \
  }

  for (int t=0; t<T; t+=2){
    STEP(t,   xrA, xrB);
    STEP(t+1, xrB, xrA);
  }
#undef STEP

  // final hidden state h_T
  out[hToff + (size_t)blk*64 + lane] = h;
}

extern "C" void kernel_launch(void* const* d_in, const int* in_sizes, int n_in,
                              void* d_out, int out_size, void* d_ws, size_t ws_size,
                              hipStream_t stream)
{
  const float* x   = (const float*)d_in[0];
  const float* fw  = (const float*)d_in[1];
  const float* ew  = (const float*)d_in[2];
  const float* eb  = (const float*)d_in[3];
  const float* exw = (const float*)d_in[4];
  const float* exb = (const float*)d_in[5];
  const float* vw  = (const float*)d_in[6];
  const float* nw  = (const float*)d_in[7];
  const float* nb  = (const float*)d_in[8];

  const long long BT = in_sizes[0] / 128;           // B*T
  const int B = (int)((long long)out_size/64 - BT); // out = B*T*64 + B*64
  const int T = (int)(BT / B);

  qssm<<<B, 64, 0, stream>>>(x, fw, ew, eb, exw, exb, vw, nw, nb,
                             (float*)d_out, T, (long long)BT*64);
}